// Round 7
// baseline (224.309 us; speedup 1.0000x reference)
//
#include <hip/hip_runtime.h>
#include <hip/hip_bf16.h>
#include <stdint.h>

// MultiHeadAttention: B=4 S=4096 D=1024 H=16 DH=64; attention is per-token 16x16
// over the head axis. Round 7: quadrant-phase GEMM (faithful m201 structure):
// per phase all 8 waves compute ONE 128x128 C-quadrant from ONE A-half + ONE
// B-half; halves free mid-tile -> continuous half-granularity staging with
// counted vmcnt(4) (never 0 in steady state). cvt pass restored for q/k/v/W.

namespace {
constexpr int kD  = 1024;
constexpr int kH  = 16;
constexpr int kDH = 64;
constexpr int kM  = 4 * 4096;             // 16384 tokens
constexpr size_t PER = (size_t)kM * kD;
constexpr size_t WSZ = (size_t)kD * kD;

typedef __attribute__((ext_vector_type(4))) float f32x4;
typedef __attribute__((ext_vector_type(8))) short s16x8;

__device__ __forceinline__ unsigned short f2b(float f) {
  uint32_t x = __builtin_bit_cast(uint32_t, f);
  x += 0x7fffu + ((x >> 16) & 1u);   // round-to-nearest-even
  return (unsigned short)(x >> 16);
}
__device__ __forceinline__ float b2f(unsigned short u) {
  return __builtin_bit_cast(float, (uint32_t)u << 16);
}

typedef __attribute__((address_space(3))) void as3_void;
typedef __attribute__((address_space(1))) void as1_void;
__device__ __forceinline__ void gload_lds16(const void* g, void* l) {
  __builtin_amdgcn_global_load_lds((const as1_void*)(uintptr_t)g,
                                   (as3_void*)(uint32_t)(uintptr_t)l, 16, 0, 0);
}

// ---------------- convert pass: 7 f32 tensors -> consecutive bf16 buffers ----
__global__ __launch_bounds__(256) void cvt_bf16(
    const float* __restrict__ q, const float* __restrict__ k, const float* __restrict__ v,
    const float* __restrict__ Wq, const float* __restrict__ Wk, const float* __restrict__ Wv,
    const float* __restrict__ Wo, unsigned short* __restrict__ out) {
  const size_t total8 = (3 * PER + 4 * WSZ) / 8;
  for (size_t i8 = (size_t)blockIdx.x * blockDim.x + threadIdx.x; i8 < total8;
       i8 += (size_t)gridDim.x * blockDim.x) {
    size_t i = i8 * 8;
    const float* s; size_t o;
    if (i < 3 * PER) {
      if (i < PER)            { s = q; o = i; }
      else if (i < 2 * PER)   { s = k; o = i - PER; }
      else                    { s = v; o = i - 2 * PER; }
    } else {
      size_t j = i - 3 * PER;
      if (j < WSZ)            { s = Wq; o = j; }
      else if (j < 2 * WSZ)   { s = Wk; o = j - WSZ; }
      else if (j < 3 * WSZ)   { s = Wv; o = j - 2 * WSZ; }
      else                    { s = Wo; o = j - 3 * WSZ; }
    }
    f32x4 f0 = ((const f32x4*)(s + o))[0];
    f32x4 f1 = ((const f32x4*)(s + o))[1];
    s16x8 r;
#pragma unroll
    for (int d = 0; d < 4; ++d) {
      r[d]     = (short)f2b(f0[d]);
      r[4 + d] = (short)f2b(f1[d]);
    }
    *(s16x8*)(out + i) = r;
  }
}

// ---------------- quadrant-phase 256x256 GEMM: C[m,n] = sum_k A[m,k]*B[n,k] --
// 8 waves; per phase the whole block computes quadrant (mh,nh) in Gray order
// (0,0),(0,1),(1,1),(1,0). Wave w owns a 32x64 sub-tile: wrow=w>>1, wcol=w&1.
// LDS = 8 half-slots x 16KB (A-half/B-half = 128 rows x 64 K bf16, XOR-swizzled).
// Stage ledger (tile t): p0: A1(t+1)->nb+1, B0(t+1)->nb+2 (slots freed in t-1);
// p2: A0(t+2)->b+0 (A0(t) last read p1, barrier passed); p3: B1(t+2)->b+3
// (B1(t) last read p2). Waits (in-order retirement): p0 vmcnt(4) retires
// B0(t) [issued t-1 p0; newer = t-1's p2+p3 = 4]; p1 vmcnt(4) retires B1(t)
// [issued t-1 p3; newer = t p0's 4] and A1(t). tt==0: 8/8 (prologue = 12
// loads); tt==KT-1: p0 vmcnt(0) (staging of t+1/t+2 skipped).
constexpr int BM2 = 256, BN2 = 256, BK2 = 64;
constexpr int KT2 = kD / BK2;   // 16 K-tiles

__device__ __forceinline__ void mfma16(f32x4 (&a)[2][4], s16x8 (&af)[2][2],
                                       s16x8 (&bw)[4][2]) {
  __builtin_amdgcn_s_setprio(1);
#pragma unroll
  for (int mi = 0; mi < 2; ++mi)
#pragma unroll
    for (int nj = 0; nj < 4; ++nj)
#pragma unroll
      for (int kk = 0; kk < 2; ++kk)
        a[mi][nj] = __builtin_amdgcn_mfma_f32_16x16x32_bf16(af[mi][kk], bw[nj][kk],
                                                            a[mi][nj], 0, 0, 0);
  __builtin_amdgcn_s_setprio(0);
}

template <bool OUT_F32>
__device__ __forceinline__ void gemmq_body(const unsigned short* __restrict__ A,
                                           const unsigned short* __restrict__ Bm,
                                           void* __restrict__ Cp) {
  constexpr int K = kD, N = kD;
  __shared__ __align__(16) unsigned short lds[65536];  // 8 slots x 8192 elems

  // XCD-bijective swizzle of the 4x64 = 256-block grid.
  const int lin = blockIdx.y * gridDim.x + blockIdx.x;
  const int xcd = lin & 7;
  const int idx = lin >> 3;
  const int m0 = (xcd * 8 + (idx >> 2)) * BM2;
  const int n0 = (idx & 3) * BN2;

  const int t    = threadIdx.x;
  const int lane = t & 63;
  const int w    = t >> 6;
  const int wrow = w >> 1;        // 0..3 (32-row band within quadrant)
  const int wcol = w & 1;         // 0..1 (64-col band within quadrant)

  const int srow  = lane >> 3;
  const int sslot = (lane & 7) ^ srow;       // pre-swizzled source slot (rule #21)
  const int fr     = lane & 15;
  const int fkslot = lane >> 4;

  auto stageHalf = [&](const unsigned short* src, int grow0, int k0, int slot) {
    const unsigned short* g = src + (size_t)(grow0 + w * 16 + srow) * K + k0 + sslot * 8;
    unsigned short* l = lds + slot * 8192 + w * 16 * 64;
    gload_lds16(g, l);
    gload_lds16(g + (size_t)8 * K, l + 8 * 64);
  };
  auto rdA = [&](int slot, int mi, int kk) -> s16x8 {
    int r = wrow * 32 + mi * 16 + fr;
    int s16 = (kk * 4 + fkslot) ^ (r & 7);
    return *(const s16x8*)(lds + slot * 8192 + r * 64 + s16 * 8);
  };
  auto rdB = [&](int slot, int nj, int kk) -> s16x8 {
    int r = wcol * 64 + nj * 16 + fr;
    int s16 = (kk * 4 + fkslot) ^ (r & 7);
    return *(const s16x8*)(lds + slot * 8192 + r * 64 + s16 * 8);
  };

  f32x4 acc[4][2][4];   // [quadrant][mi][nj]
#pragma unroll
  for (int qi = 0; qi < 4; ++qi)
#pragma unroll
    for (int mi = 0; mi < 2; ++mi)
#pragma unroll
      for (int nj = 0; nj < 4; ++nj) acc[qi][mi][nj] = (f32x4){0.f, 0.f, 0.f, 0.f};

  // prologue: A0(0),B0(0),B1(0),A1(0),A0(1),B1(1) — order matters for the waits
  stageHalf(A,  m0,       0, 0);
  stageHalf(Bm, n0,       0, 2);
  stageHalf(Bm, n0 + 128, 0, 3);
  stageHalf(A,  m0 + 128, 0, 1);
  stageHalf(A,  m0,       BK2, 4);
  stageHalf(Bm, n0 + 128, BK2, 7);

  s16x8 af[2][2], bw[4][2];

  for (int tt = 0; tt < KT2; ++tt) {
    const int b  = (tt & 1) * 4;   // this tile's slot base
    const int nb = b ^ 4;          // next tile's slot base
    const int k1 = (tt + 1) * BK2;
    const int k2 = (tt + 2) * BK2;

    // -------- phase 0: quadrant (0,0) — A0 + B0 --------
    if (tt == 0)            { asm volatile("s_waitcnt vmcnt(8)" ::: "memory"); }
    else if (tt == KT2 - 1) { asm volatile("s_waitcnt vmcnt(0)" ::: "memory"); }
    else                    { asm volatile("s_waitcnt vmcnt(4)" ::: "memory"); }
    __builtin_amdgcn_s_barrier();
#pragma unroll
    for (int mi = 0; mi < 2; ++mi)
#pragma unroll
      for (int kk = 0; kk < 2; ++kk) af[mi][kk] = rdA(b + 0, mi, kk);
#pragma unroll
    for (int nj = 0; nj < 4; ++nj)
#pragma unroll
      for (int kk = 0; kk < 2; ++kk) bw[nj][kk] = rdB(b + 2, nj, kk);
    if (tt + 1 < KT2) {
      stageHalf(A,  m0 + 128, k1, nb + 1);   // A1(t+1)
      stageHalf(Bm, n0,       k1, nb + 2);   // B0(t+1)
    }
    asm volatile("s_waitcnt lgkmcnt(0)" ::: "memory");
    __builtin_amdgcn_sched_barrier(0);
    mfma16(acc[0], af, bw);

    // -------- phase 1: quadrant (0,1) — A0 (held) + B1 --------
    if (tt == 0) { asm volatile("s_waitcnt vmcnt(8)" ::: "memory"); }
    else         { asm volatile("s_waitcnt vmcnt(4)" ::: "memory"); }
    __builtin_amdgcn_s_barrier();
#pragma unroll
    for (int nj = 0; nj < 4; ++nj)
#pragma unroll
      for (int kk = 0; kk < 2; ++kk) bw[nj][kk] = rdB(b + 3, nj, kk);
    asm volatile("s_waitcnt lgkmcnt(0)" ::: "memory");
    __builtin_amdgcn_sched_barrier(0);
    mfma16(acc[1], af, bw);

    // -------- phase 2: quadrant (1,1) — A1 + B1 (held) --------
    __builtin_amdgcn_s_barrier();
#pragma unroll
    for (int mi = 0; mi < 2; ++mi)
#pragma unroll
      for (int kk = 0; kk < 2; ++kk) af[mi][kk] = rdA(b + 1, mi, kk);
    if (tt + 2 < KT2) stageHalf(A, m0, k2, b + 0);        // A0(t+2) over freed A0(t)
    asm volatile("s_waitcnt lgkmcnt(0)" ::: "memory");
    __builtin_amdgcn_sched_barrier(0);
    mfma16(acc[2], af, bw);

    // -------- phase 3: quadrant (1,0) — A1 (held) + B0 --------
    __builtin_amdgcn_s_barrier();
#pragma unroll
    for (int nj = 0; nj < 4; ++nj)
#pragma unroll
      for (int kk = 0; kk < 2; ++kk) bw[nj][kk] = rdB(b + 2, nj, kk);
    if (tt + 2 < KT2) stageHalf(Bm, n0 + 128, k2, b + 3); // B1(t+2) over freed B1(t)
    asm volatile("s_waitcnt lgkmcnt(0)" ::: "memory");
    __builtin_amdgcn_sched_barrier(0);
    mfma16(acc[3], af, bw);
  }

  // C/D layout: col = lane&15, row = (lane>>4)*4 + r   [verified rounds 1-6]
  constexpr int MH[4] = {0, 0, 1, 1};
  constexpr int NH[4] = {0, 1, 1, 0};
  const int cr = (lane >> 4) * 4;
  const int cc = lane & 15;
#pragma unroll
  for (int qi = 0; qi < 4; ++qi)
#pragma unroll
    for (int mi = 0; mi < 2; ++mi)
#pragma unroll
      for (int nj = 0; nj < 4; ++nj)
#pragma unroll
        for (int r = 0; r < 4; ++r) {
          size_t row = (size_t)(m0 + MH[qi] * 128 + wrow * 32 + mi * 16 + cr + r);
          size_t col = (size_t)(n0 + NH[qi] * 128 + wcol * 64 + nj * 16 + cc);
          if constexpr (OUT_F32)
            ((float*)Cp)[row * N + col] = acc[qi][mi][nj][r];
          else
            ((unsigned short*)Cp)[row * N + col] = f2b(acc[qi][mi][nj][r]);
        }
}

__global__ __launch_bounds__(512, 2) void proj_gemmq(
    const unsigned short* __restrict__ qb, const unsigned short* __restrict__ kb,
    const unsigned short* __restrict__ vb, const unsigned short* __restrict__ Wqb,
    const unsigned short* __restrict__ Wkb, const unsigned short* __restrict__ Wvb,
    unsigned short* __restrict__ qh, unsigned short* __restrict__ kh,
    unsigned short* __restrict__ vh) {
  const unsigned short *A, *W;
  unsigned short* C;
  if (blockIdx.z == 0)      { A = qb; W = Wqb; C = qh; }
  else if (blockIdx.z == 1) { A = kb; W = Wkb; C = kh; }
  else                      { A = vb; W = Wvb; C = vh; }
  gemmq_body<false>(A, W, C);
}

__global__ __launch_bounds__(512, 2) void out_gemmq(const unsigned short* __restrict__ attn,
                                                    const unsigned short* __restrict__ Wob,
                                                    float* __restrict__ out) {
  gemmq_body<true>(attn, Wob, out);
}

// ---------------- per-token head-axis attention (verified rounds 1-6) --------
__global__ __launch_bounds__(256) void attn_tok(const unsigned short* __restrict__ qh,
                                                const unsigned short* __restrict__ kh,
                                                const unsigned short* __restrict__ vh,
                                                const float* __restrict__ mask,
                                                unsigned short* __restrict__ attn) {
  __shared__ float P[4][16][17];
  __shared__ __align__(16) unsigned short Vs[4][16 * 64];
  const int lane = threadIdx.x & 63;
  const int wid  = threadIdx.x >> 6;
  const size_t tok = (size_t)blockIdx.x * 4 + wid;

  const unsigned short* qp = qh + tok * kD;
  const unsigned short* kp = kh + tok * kD;
  const unsigned short* vp = vh + tok * kD;

  {
    const s16x8* src = (const s16x8*)vp;
    s16x8 a = src[2 * lane], b = src[2 * lane + 1];
    s16x8* dst = (s16x8*)Vs[wid];
    dst[2 * lane] = a;
    dst[2 * lane + 1] = b;
  }

  const int fr = lane & 15;
  const int fk = (lane >> 4) * 8;
  s16x8 a0 = *(const s16x8*)(qp + fr * kDH + fk);
  s16x8 a1 = *(const s16x8*)(qp + fr * kDH + 32 + fk);
  s16x8 b0 = *(const s16x8*)(kp + fr * kDH + fk);
  s16x8 b1 = *(const s16x8*)(kp + fr * kDH + 32 + fk);
  f32x4 s = {0.f, 0.f, 0.f, 0.f};
  s = __builtin_amdgcn_mfma_f32_16x16x32_bf16(a0, b0, s, 0, 0, 0);
  s = __builtin_amdgcn_mfma_f32_16x16x32_bf16(a1, b1, s, 0, 0, 0);

  const int cr = (lane >> 4) * 4;
  const int cc = lane & 15;
  float p[4];
#pragma unroll
  for (int r = 0; r < 4; ++r) {
    float val = s[r] * 0.125f * mask[(cr + r) * kH + cc];
    float mx = val;
#pragma unroll
    for (int d = 1; d < 16; d <<= 1) mx = fmaxf(mx, __shfl_xor(mx, d));
    float e = __expf(val - mx);
    float sum = e;
#pragma unroll
    for (int d = 1; d < 16; d <<= 1) sum += __shfl_xor(sum, d);
    p[r] = e / sum;
  }
#pragma unroll
  for (int r = 0; r < 4; ++r) P[wid][cr + r][cc] = p[r];

  const int h  = lane >> 2;
  const int d0 = (lane & 3) * 16;
  float o[16];
#pragma unroll
  for (int i = 0; i < 16; ++i) o[i] = 0.f;
#pragma unroll
  for (int g = 0; g < 16; ++g) {
    float pg = P[wid][h][g];
    s16x8 v0 = *(const s16x8*)(Vs[wid] + g * kDH + d0);
    s16x8 v1 = *(const s16x8*)(Vs[wid] + g * kDH + d0 + 8);
#pragma unroll
    for (int dd = 0; dd < 8; ++dd) {
      o[dd]     += pg * b2f((unsigned short)v0[dd]);
      o[8 + dd] += pg * b2f((unsigned short)v1[dd]);
    }
  }
  unsigned short* op = attn + tok * kD + h * kDH + d0;
  s16x8 r0, r1;
#pragma unroll
  for (int dd = 0; dd < 8; ++dd) {
    r0[dd] = (short)f2b(o[dd]);
    r1[dd] = (short)f2b(o[dd + 8]);
  }
  *(s16x8*)op = r0;
  *(s16x8*)(op + 8) = r1;
}

// ---------------- fallback (round-1 verified path, fused-cvt GEMM) ----------
constexpr int BM = 128, BN = 128, BK = 32;
constexpr int LDSP = BK + 8;
__device__ __forceinline__ void cvt16_store(const float* __restrict__ g, short* __restrict__ l) {
  const f32x4* s4 = (const f32x4*)g;
  f32x4 f0 = s4[0], f1 = s4[1], f2 = s4[2], f3 = s4[3];
  s16x8 o0, o1;
#pragma unroll
  for (int i = 0; i < 4; ++i) {
    o0[i]     = (short)f2b(f0[i]);
    o0[4 + i] = (short)f2b(f1[i]);
    o1[i]     = (short)f2b(f2[i]);
    o1[4 + i] = (short)f2b(f3[i]);
  }
  *(s16x8*)l = o0;
  *(s16x8*)(l + 8) = o1;
}

template <bool A_BF16, bool OUT_F32>
__device__ __forceinline__ void gemm_body_cvt(const void* __restrict__ Ap,
                                              const float* __restrict__ Wp,
                                              void* __restrict__ Cp) {
  constexpr int N = kD, K = kD;
  __shared__ short As[BM * LDSP];
  __shared__ short Bs[BN * LDSP];
  const int t  = threadIdx.x;
  const int m0 = blockIdx.y * BM;
  const int n0 = blockIdx.x * BN;
  const int srow = t >> 1;
  const int scol = (t & 1) * 16;
  const int lane = t & 63;
  const int wid  = t >> 6;
  const int wm   = (wid >> 1) * 64;
  const int wn   = (wid & 1) * 64;
  const int fr   = lane & 15;
  const int fk   = (lane >> 4) * 8;

  f32x4 acc[4][4];
#pragma unroll
  for (int i = 0; i < 4; ++i)
#pragma unroll
    for (int j = 0; j < 4; ++j) acc[i][j] = (f32x4){0.f, 0.f, 0.f, 0.f};

  for (int k0 = 0; k0 < K; k0 += BK) {
    if constexpr (A_BF16) {
      const unsigned short* Ab = (const unsigned short*)Ap;
      const s16x8* src = (const s16x8*)(Ab + (size_t)(m0 + srow) * K + k0 + scol);
      s16x8 v0 = src[0], v1 = src[1];
      *(s16x8*)(As + srow * LDSP + scol) = v0;
      *(s16x8*)(As + srow * LDSP + scol + 8) = v1;
    } else {
      cvt16_store((const float*)Ap + (size_t)(m0 + srow) * K + k0 + scol,
                  As + srow * LDSP + scol);
    }
    cvt16_store(Wp + (size_t)(n0 + srow) * K + k0 + scol, Bs + srow * LDSP + scol);
    __syncthreads();
    s16x8 af[4], bw[4];
#pragma unroll
    for (int i = 0; i < 4; ++i)
      af[i] = *(const s16x8*)(As + (wm + i * 16 + fr) * LDSP + fk);
#pragma unroll
    for (int j = 0; j < 4; ++j)
      bw[j] = *(const s16x8*)(Bs + (wn + j * 16 + fr) * LDSP + fk);
#pragma unroll
    for (int i = 0; i < 4; ++i)
#pragma unroll
      for (int j = 0; j < 4; ++j)
        acc[i][j] = __builtin_amdgcn_mfma_f32_16x16x32_bf16(af[i], bw[j], acc[i][j], 0, 0, 0);
    __syncthreads();
  }
  const int cr = (lane >> 4) * 4;
  const int cc = lane & 15;
#pragma unroll
  for (int i = 0; i < 4; ++i)
#pragma unroll
    for (int j = 0; j < 4; ++j)
#pragma unroll
      for (int r = 0; r < 4; ++r) {
        size_t row = (size_t)(m0 + wm + i * 16 + cr + r);
        size_t col = (size_t)(n0 + wn + j * 16 + cc);
        if constexpr (OUT_F32)
          ((float*)Cp)[row * N + col] = acc[i][j][r];
        else
          ((unsigned short*)Cp)[row * N + col] = f2b(acc[i][j][r]);
      }
}

__global__ __launch_bounds__(256) void proj_gemm_cvt(
    const float* __restrict__ q, const float* __restrict__ k, const float* __restrict__ v,
    const float* __restrict__ Wq, const float* __restrict__ Wk, const float* __restrict__ Wv,
    unsigned short* __restrict__ qh, unsigned short* __restrict__ kh,
    unsigned short* __restrict__ vh) {
  const float* A; const float* W; unsigned short* C;
  if (blockIdx.z == 0)      { A = q; W = Wq; C = qh; }
  else if (blockIdx.z == 1) { A = k; W = Wk; C = kh; }
  else                      { A = v; W = Wv; C = vh; }
  gemm_body_cvt<false, false>(A, W, C);
}

__global__ __launch_bounds__(256) void out_gemm_cvt(const unsigned short* __restrict__ attn,
                                                    const float* __restrict__ Wo,
                                                    float* __restrict__ out) {
  gemm_body_cvt<true, true>(attn, Wo, out);
}

}  // namespace

extern "C" void kernel_launch(void* const* d_in, const int* in_sizes, int n_in,
                              void* d_out, int out_size, void* d_ws, size_t ws_size,
                              hipStream_t stream) {
  (void)in_sizes; (void)n_in; (void)out_size;
  const float* q    = (const float*)d_in[0];
  const float* k    = (const float*)d_in[1];
  const float* v    = (const float*)d_in[2];
  const float* mask = (const float*)d_in[3];
  const float* Wq   = (const float*)d_in[4];
  const float* Wk   = (const float*)d_in[5];
  const float* Wv   = (const float*)d_in[6];
  const float* Wo   = (const float*)d_in[7];

  const size_t need = (6 * PER + 4 * WSZ) * sizeof(unsigned short);  // ~210 MB
  if (ws_size >= need) {
    unsigned short* qb  = (unsigned short*)d_ws;   // qb kb vb | Wq Wk Wv Wo | qh kh vh
    unsigned short* kb  = qb + PER;
    unsigned short* vb  = kb + PER;
    unsigned short* Wqb = vb + PER;
    unsigned short* Wkb = Wqb + WSZ;
    unsigned short* Wvb = Wkb + WSZ;
    unsigned short* Wob = Wvb + WSZ;
    unsigned short* qh  = Wob + WSZ;
    unsigned short* kh  = qh + PER;
    unsigned short* vh  = kh + PER;
    unsigned short* at  = qb;  // alias: qb dead after proj_gemmq (stream-ordered)

    cvt_bf16<<<2048, 256, 0, stream>>>(q, k, v, Wq, Wk, Wv, Wo, qb);
    proj_gemmq<<<dim3(kD / BN2, kM / BM2, 3), 512, 0, stream>>>(qb, kb, vb, Wqb, Wkb, Wvb,
                                                                qh, kh, vh);
    attn_tok<<<dim3(kM / 4), 256, 0, stream>>>(qh, kh, vh, mask, at);
    out_gemmq<<<dim3(kD / BN2, kM / BM2), 512, 0, stream>>>(at, Wob, (float*)d_out);
  } else {
    // round-1 verified fallback (fused-convert GEMMs)
    unsigned short* qh = (unsigned short*)d_ws;
    unsigned short* kh = qh + PER;
    unsigned short* vh = kh + PER;
    unsigned short* at = (ws_size >= 4 * PER * sizeof(unsigned short)) ? (vh + PER) : qh;
    proj_gemm_cvt<<<dim3(kD / BN, kM / BM, 3), 256, 0, stream>>>(q, k, v, Wq, Wk, Wv,
                                                                 qh, kh, vh);
    attn_tok<<<dim3(kM / 4), 256, 0, stream>>>(qh, kh, vh, mask, at);
    out_gemm_cvt<<<dim3(kD / BN, kM / BM), 256, 0, stream>>>(at, Wo, (float*)d_out);
  }
}